// Round 2
// baseline (100.508 us; speedup 1.0000x reference)
//
#include <hip/hip_runtime.h>

#define LN_EPS 1e-5f

__device__ __forceinline__ void wave_reduce(float& s1, float& s2) {
  #pragma unroll
  for (int off = 32; off; off >>= 1) {
    s1 += __shfl_xor(s1, off);
    s2 += __shfl_xor(s2, off);
  }
}

// copy one 1024-float row (global<->LDS or LDS->global), gt threads participate
__device__ __forceinline__ void copy_tile(int ug, int gt,
                                          const float* __restrict__ src,
                                          float* __restrict__ dst) {
  for (int ff = ug; ff < 256; ff += gt)
    ((float4*)dst)[ff] = ((const float4*)src)[ff];
}

__device__ __forceinline__ void stage_params(int u, int nthr,
    const float* __restrict__ g, const float* __restrict__ b,
    const float* __restrict__ Ww, const float* __restrict__ Wb,
    float* gl, float* bl, float* Wt, float* wb) {
  for (int f = u; f < 256; f += nthr) ((float4*)gl)[f] = ((const float4*)g)[f];
  for (int f = u; f < 256; f += nthr) ((float4*)bl)[f] = ((const float4*)b)[f];
  for (int f = u; f < 256; f += nthr) {
    float4 w = ((const float4*)Ww)[f];
    int m = f >> 3;            // row of Ww
    int l0 = (f & 7) * 4;      // col of Ww
    Wt[(l0 + 0) * 32 + m] = w.x;   // Wt[l][m] = Ww[m][l]
    Wt[(l0 + 1) * 32 + m] = w.y;
    Wt[(l0 + 2) * 32 + m] = w.z;
    Wt[(l0 + 3) * 32 + m] = w.w;
  }
  if (u < 32) wb[u] = Wb[u];
}

// One tree node on a group of NW waves. Children in Lt/Rt, C pre-staged in Ot.
// Result h (LN+ReLU) overwrites Ot. T1 scratch goes into Lt (dead after mm1),
// T2 overwrites C in Ot. All barriers are block-wide; every step keeps all
// waves of the block active so barriers are uniform.
template <int NW>
__device__ void node_compute(int ug, int wv, int wgrp,
    float* __restrict__ Lt, float* __restrict__ Rt, float* __restrict__ Ot,
    const float* __restrict__ Wt, const float* __restrict__ wb,
    const float* __restrict__ gl, const float* __restrict__ bl,
    float* red_s, float* red_ss) {
  constexpr int R = 16 / NW;     // outputs per thread
  constexpr int RS = 2 * NW;     // row stride between a thread's rows
  const int j = ug & 31;
  const int ib = ug >> 5;        // [0, 2*NW)
  float acc[R];

  // ---- T1 = L @ R ----
  #pragma unroll
  for (int s = 0; s < R; ++s) acc[s] = 0.f;
  #pragma unroll
  for (int k0 = 0; k0 < 32; k0 += 4) {
    float4 a[R];
    #pragma unroll
    for (int s = 0; s < R; ++s)
      a[s] = *(const float4*)&Lt[(ib + s * RS) * 32 + k0];
    #pragma unroll
    for (int kk = 0; kk < 4; ++kk) {
      float bv = Rt[(k0 + kk) * 32 + j];
      #pragma unroll
      for (int s = 0; s < R; ++s)
        acc[s] = fmaf(((const float*)&a[s])[kk], bv, acc[s]);
    }
  }
  __syncthreads();
  #pragma unroll
  for (int s = 0; s < R; ++s) Lt[(ib + s * RS) * 32 + j] = acc[s];
  __syncthreads();

  // ---- T2 = T1 @ C  (T1 in Lt, C in Ot) ----
  #pragma unroll
  for (int s = 0; s < R; ++s) acc[s] = 0.f;
  #pragma unroll
  for (int k0 = 0; k0 < 32; k0 += 4) {
    float4 a[R];
    #pragma unroll
    for (int s = 0; s < R; ++s)
      a[s] = *(const float4*)&Lt[(ib + s * RS) * 32 + k0];
    #pragma unroll
    for (int kk = 0; kk < 4; ++kk) {
      float bv = Ot[(k0 + kk) * 32 + j];
      #pragma unroll
      for (int s = 0; s < R; ++s)
        acc[s] = fmaf(((const float*)&a[s])[kk], bv, acc[s]);
    }
  }
  __syncthreads();
  #pragma unroll
  for (int s = 0; s < R; ++s) Ot[(ib + s * RS) * 32 + j] = acc[s];
  __syncthreads();

  // ---- X = T2 @ Ww^T + Wb  (T2 in Ot, Wt[l][j] = Ww[j][l]) ----
  #pragma unroll
  for (int s = 0; s < R; ++s) acc[s] = wb[j];
  #pragma unroll
  for (int k0 = 0; k0 < 32; k0 += 4) {
    float4 a[R];
    #pragma unroll
    for (int s = 0; s < R; ++s)
      a[s] = *(const float4*)&Ot[(ib + s * RS) * 32 + k0];
    #pragma unroll
    for (int kk = 0; kk < 4; ++kk) {
      float bv = Wt[(k0 + kk) * 32 + j];
      #pragma unroll
      for (int s = 0; s < R; ++s)
        acc[s] = fmaf(((const float*)&a[s])[kk], bv, acc[s]);
    }
  }

  // ---- LayerNorm over 1024 + gamma/beta + ReLU ----
  float s1 = 0.f, s2 = 0.f;
  #pragma unroll
  for (int s = 0; s < R; ++s) { s1 += acc[s]; s2 += acc[s] * acc[s]; }
  wave_reduce(s1, s2);
  if ((ug & 63) == 0) { red_s[wv] = s1; red_ss[wv] = s2; }
  __syncthreads();   // also guarantees all matmul3 reads of Ot are done
  float S = 0.f, SS = 0.f;
  #pragma unroll
  for (int w = 0; w < NW; ++w) { S += red_s[wgrp + w]; SS += red_ss[wgrp + w]; }
  const float mu = S * (1.0f / 1024.0f);
  const float rs = rsqrtf(SS * (1.0f / 1024.0f) - mu * mu + LN_EPS);
  #pragma unroll
  for (int s = 0; s < R; ++s) {
    int row = ib + s * RS;
    int idx = row * 32 + j;
    float y = (acc[s] - mu) * rs * gl[idx] + bl[idx];
    Ot[row * 32 + j] = fmaxf(y, 0.f);
  }
  __syncthreads();
}

// ---- K1: leaves (level 10) + level 9 + level 8; 256 blocks x 512 thr ----
__global__ __launch_bounds__(512) void k_bottom(
    const int* __restrict__ word_ids, const float* __restrict__ emb,
    const float* __restrict__ Ww, const float* __restrict__ Wb,
    const float* __restrict__ g, const float* __restrict__ b,
    float* __restrict__ h8) {
  __shared__ float pool[6 * 1024];
  __shared__ float gl[1024], bl[1024], Wt[1024], wb[32];
  __shared__ float red_s[16], red_ss[16];
  const int u = threadIdx.x;
  const int blk = blockIdx.x;
  const int wv = u >> 6;

  stage_params(u, 512, g, b, Ww, Wb, gl, bl, Wt, wb);

  // leaves: 4 per block, 2 waves each
  {
    const int l = u >> 7;          // 0..3
    const int v = u & 127;
    const int wid = word_ids[1023 + blk * 4 + l];
    const float4* src = (const float4*)(emb + (size_t)wid * 1024);
    float4 x0 = src[v], x1 = src[v + 128];
    float s1 = (x0.x + x0.y) + (x0.z + x0.w) + (x1.x + x1.y) + (x1.z + x1.w);
    float s2 = x0.x * x0.x + x0.y * x0.y + x0.z * x0.z + x0.w * x0.w +
               x1.x * x1.x + x1.y * x1.y + x1.z * x1.z + x1.w * x1.w;
    wave_reduce(s1, s2);
    if ((u & 63) == 0) { red_s[wv] = s1; red_ss[wv] = s2; }
    __syncthreads();  // red visible; also params staged
    const float S = red_s[2 * l] + red_s[2 * l + 1];
    const float SS = red_ss[2 * l] + red_ss[2 * l + 1];
    const float mu = S * (1.0f / 1024.0f);
    const float rs = rsqrtf(SS * (1.0f / 1024.0f) - mu * mu + LN_EPS);
    float* tp = pool + l * 1024;
    float4 g4 = ((const float4*)gl)[v], b4 = ((const float4*)bl)[v];
    float4 y;
    y.x = fmaxf((x0.x - mu) * rs * g4.x + b4.x, 0.f);
    y.y = fmaxf((x0.y - mu) * rs * g4.y + b4.y, 0.f);
    y.z = fmaxf((x0.z - mu) * rs * g4.z + b4.z, 0.f);
    y.w = fmaxf((x0.w - mu) * rs * g4.w + b4.w, 0.f);
    ((float4*)tp)[v] = y;
    g4 = ((const float4*)gl)[v + 128]; b4 = ((const float4*)bl)[v + 128];
    y.x = fmaxf((x1.x - mu) * rs * g4.x + b4.x, 0.f);
    y.y = fmaxf((x1.y - mu) * rs * g4.y + b4.y, 0.f);
    y.z = fmaxf((x1.z - mu) * rs * g4.z + b4.z, 0.f);
    y.w = fmaxf((x1.w - mu) * rs * g4.w + b4.w, 0.f);
    ((float4*)tp)[v + 128] = y;
    __syncthreads();
  }

  // level 9: 2 nodes, NW=4 each
  {
    const int m = u >> 8;          // 0..1
    const int ug = u & 255;
    const int id = 511 + blk * 2 + m;
    float* Ot = pool + (4 + m) * 1024;
    copy_tile(ug, 256, emb + (size_t)word_ids[id] * 1024, Ot);
    node_compute<4>(ug, wv, m * 4, pool + (2 * m) * 1024,
                    pool + (2 * m + 1) * 1024, Ot, Wt, wb, gl, bl, red_s, red_ss);
  }

  // level 8: 1 node, NW=8 (tile 0 is dead, reuse for C/output)
  {
    const int id = 255 + blk;
    float* Ot = pool;
    copy_tile(u, 512, emb + (size_t)word_ids[id] * 1024, Ot);
    node_compute<8>(u, wv, 0, pool + 4 * 1024, pool + 5 * 1024, Ot, Wt, wb, gl,
                    bl, red_s, red_ss);
  }

  copy_tile(u, 512, pool, h8 + (size_t)blk * 1024);
}

// ---- K2/K3: four level-steps from d_top down; optional fused head ----
__global__ __launch_bounds__(1024) void k_quad(
    const int* __restrict__ word_ids, const float* __restrict__ emb,
    const float* __restrict__ Ww, const float* __restrict__ Wb,
    const float* __restrict__ g, const float* __restrict__ b,
    const float* __restrict__ Pw, const float* __restrict__ Pb,
    const int* __restrict__ label, const float* __restrict__ h_in,
    float* __restrict__ h_out, float* __restrict__ out, int d_top) {
  extern __shared__ float smem[];
  float* pool = smem;                 // 24 tiles x 1024
  float* gl = pool + 24 * 1024;
  float* bl = gl + 1024;
  float* Wt = bl + 1024;
  float* wb = Wt + 1024;
  float* red_s = wb + 32;
  float* red_ss = red_s + 16;

  const int u = threadIdx.x;
  const int blk = blockIdx.x;
  const int wv = u >> 6;

  stage_params(u, 1024, g, b, Ww, Wb, gl, bl, Wt, wb);
  copy_tile(u & 63, 64, h_in + (size_t)(blk * 16 + wv) * 1024, pool + wv * 1024);
  __syncthreads();

  // step 0: 8 nodes, NW=2; children tiles 0..15, outputs 16..23
  {
    const int m = u >> 7, ug = u & 127;
    const int id = (1 << d_top) - 1 + blk * 8 + m;
    float* Ot = pool + (16 + m) * 1024;
    copy_tile(ug, 128, emb + (size_t)word_ids[id] * 1024, Ot);
    node_compute<2>(ug, wv, m * 2, pool + (2 * m) * 1024,
                    pool + (2 * m + 1) * 1024, Ot, Wt, wb, gl, bl, red_s, red_ss);
  }
  // step 1: 4 nodes, NW=4; children 16..23, outputs 0..3
  {
    const int m = u >> 8, ug = u & 255;
    const int id = (1 << (d_top - 1)) - 1 + blk * 4 + m;
    float* Ot = pool + m * 1024;
    copy_tile(ug, 256, emb + (size_t)word_ids[id] * 1024, Ot);
    node_compute<4>(ug, wv, m * 4, pool + (16 + 2 * m) * 1024,
                    pool + (16 + 2 * m + 1) * 1024, Ot, Wt, wb, gl, bl, red_s,
                    red_ss);
  }
  // step 2: 2 nodes, NW=8; children 0..3, outputs 16..17
  {
    const int m = u >> 9, ug = u & 511;
    const int id = (1 << (d_top - 2)) - 1 + blk * 2 + m;
    float* Ot = pool + (16 + m) * 1024;
    copy_tile(ug, 512, emb + (size_t)word_ids[id] * 1024, Ot);
    node_compute<8>(ug, wv, m * 8, pool + (2 * m) * 1024,
                    pool + (2 * m + 1) * 1024, Ot, Wt, wb, gl, bl, red_s, red_ss);
  }
  // step 3: 1 node, NW=16; children 16,17, output 0
  {
    const int id = (1 << (d_top - 3)) - 1 + blk;
    float* Ot = pool;
    copy_tile(u, 1024, emb + (size_t)word_ids[id] * 1024, Ot);
    node_compute<16>(u, wv, 0, pool + 16 * 1024, pool + 17 * 1024, Ot, Wt, wb,
                     gl, bl, red_s, red_ss);
  }

  if (h_out) {
    copy_tile(u, 1024, pool, h_out + (size_t)blk * 1024);
  } else {
    // head: root in pool tile 0
    if (wv < 10) {
      const int lane = u & 63;
      float p = 0.f;
      #pragma unroll
      for (int q = 0; q < 16; ++q) {
        int e = q * 64 + lane;
        p += pool[e] * Pw[wv * 1024 + e];
      }
      #pragma unroll
      for (int off = 32; off; off >>= 1) p += __shfl_xor(p, off);
      if (lane == 0) red_s[wv] = p;
    }
    __syncthreads();
    if (u == 0) {
      float logits[10];
      #pragma unroll
      for (int c = 0; c < 10; ++c) logits[c] = red_s[c] + Pb[c];
      float mmax = logits[0];
      int am = 0;
      #pragma unroll
      for (int c = 1; c < 10; ++c)
        if (logits[c] > mmax) { mmax = logits[c]; am = c; }
      float sum = 0.f;
      #pragma unroll
      for (int c = 0; c < 10; ++c) sum += expf(logits[c] - mmax);
      float loss = -(logits[label[0]] - mmax - logf(sum));
      out[0] = (float)am;
      out[1] = loss;
    }
  }
}

extern "C" void kernel_launch(void* const* d_in, const int* in_sizes, int n_in,
                              void* d_out, int out_size, void* d_ws, size_t ws_size,
                              hipStream_t stream) {
  const int* word_ids = (const int*)d_in[0];
  const int* label = (const int*)d_in[1];
  const float* emb = (const float*)d_in[2];
  const float* Ww = (const float*)d_in[3];
  const float* Wb = (const float*)d_in[4];
  const float* g = (const float*)d_in[5];
  const float* b = (const float*)d_in[6];
  const float* Pw = (const float*)d_in[7];
  const float* Pb = (const float*)d_in[8];
  float* out = (float*)d_out;

  float* h8 = (float*)d_ws;               // 256 tiles
  float* h4 = h8 + 256 * 1024;            // 16 tiles

  const size_t QUAD_SMEM = (24 * 1024 + 3 * 1024 + 64) * sizeof(float);
  (void)hipFuncSetAttribute((const void*)k_quad,
                            hipFuncAttributeMaxDynamicSharedMemorySize,
                            (int)QUAD_SMEM);

  k_bottom<<<256, 512, 0, stream>>>(word_ids, emb, Ww, Wb, g, b, h8);
  k_quad<<<16, 1024, QUAD_SMEM, stream>>>(word_ids, emb, Ww, Wb, g, b, Pw, Pb,
                                          label, h8, h4, out, 7);
  k_quad<<<1, 1024, QUAD_SMEM, stream>>>(word_ids, emb, Ww, Wb, g, b, Pw, Pb,
                                         label, h4, nullptr, out, 3);
}

// Round 3
// 82.573 us; speedup vs baseline: 1.2172x; 1.2172x over previous
//
#include <hip/hip_runtime.h>

#define LN_EPS 1e-5f

__device__ __forceinline__ void wave_reduce(float& s1, float& s2) {
  #pragma unroll
  for (int off = 32; off; off >>= 1) {
    s1 += __shfl_xor(s1, off);
    s2 += __shfl_xor(s2, off);
  }
}

// copy one 1024-float tile; threads ug in [0,gt) participate
__device__ __forceinline__ void copy_tile(int ug, int gt,
                                          const float* __restrict__ src,
                                          float* __restrict__ dst) {
  for (int ff = ug; ff < 256; ff += gt)
    ((float4*)dst)[ff] = ((const float4*)src)[ff];
}

__device__ __forceinline__ void stage_params(int u, int nthr,
    const float* __restrict__ g, const float* __restrict__ b,
    const float* __restrict__ Ww, const float* __restrict__ Wb,
    float* gl, float* bl, float* Wt, float* wb) {
  for (int f = u; f < 256; f += nthr) ((float4*)gl)[f] = ((const float4*)g)[f];
  for (int f = u; f < 256; f += nthr) ((float4*)bl)[f] = ((const float4*)b)[f];
  for (int f = u; f < 256; f += nthr) {
    float4 w = ((const float4*)Ww)[f];
    int m = f >> 3;            // row of Ww
    int l0 = (f & 7) * 4;      // col of Ww
    Wt[(l0 + 0) * 32 + m] = w.x;   // Wt[l][m] = Ww[m][l]
    Wt[(l0 + 1) * 32 + m] = w.y;
    Wt[(l0 + 2) * 32 + m] = w.z;
    Wt[(l0 + 3) * 32 + m] = w.w;
  }
  if (u < 32) wb[u] = Wb[u];
}

// One tree node on NW waves (NW=4 -> R=4, NW=8 -> R=2; register-light only).
// Children in Lt/Rt, C pre-staged in Ot. Output (LN+ReLU) overwrites Ot.
// T1 scratch trashes Lt. All barriers block-wide and uniform across groups.
template <int NW>
__device__ void node_compute(int ug, int wv, int wgrp,
    float* __restrict__ Lt, float* __restrict__ Rt, float* __restrict__ Ot,
    const float* __restrict__ Wt, const float* __restrict__ wb,
    const float* __restrict__ gl, const float* __restrict__ bl,
    float* red_s, float* red_ss) {
  constexpr int R = 16 / NW;     // outputs per thread (<=4 by construction)
  constexpr int RS = 2 * NW;     // row stride between a thread's rows
  const int j = ug & 31;
  const int ib = ug >> 5;        // [0, 2*NW)
  float acc[R];

  // ---- T1 = L @ R ----
  #pragma unroll
  for (int s = 0; s < R; ++s) acc[s] = 0.f;
  #pragma unroll
  for (int k0 = 0; k0 < 32; k0 += 4) {
    float4 a[R];
    #pragma unroll
    for (int s = 0; s < R; ++s)
      a[s] = *(const float4*)&Lt[(ib + s * RS) * 32 + k0];
    #pragma unroll
    for (int kk = 0; kk < 4; ++kk) {
      float bv = Rt[(k0 + kk) * 32 + j];
      #pragma unroll
      for (int s = 0; s < R; ++s)
        acc[s] = fmaf(((const float*)&a[s])[kk], bv, acc[s]);
    }
  }
  __syncthreads();
  #pragma unroll
  for (int s = 0; s < R; ++s) Lt[(ib + s * RS) * 32 + j] = acc[s];
  __syncthreads();

  // ---- T2 = T1 @ C  (T1 in Lt, C in Ot) ----
  #pragma unroll
  for (int s = 0; s < R; ++s) acc[s] = 0.f;
  #pragma unroll
  for (int k0 = 0; k0 < 32; k0 += 4) {
    float4 a[R];
    #pragma unroll
    for (int s = 0; s < R; ++s)
      a[s] = *(const float4*)&Lt[(ib + s * RS) * 32 + k0];
    #pragma unroll
    for (int kk = 0; kk < 4; ++kk) {
      float bv = Ot[(k0 + kk) * 32 + j];
      #pragma unroll
      for (int s = 0; s < R; ++s)
        acc[s] = fmaf(((const float*)&a[s])[kk], bv, acc[s]);
    }
  }
  __syncthreads();
  #pragma unroll
  for (int s = 0; s < R; ++s) Ot[(ib + s * RS) * 32 + j] = acc[s];
  __syncthreads();

  // ---- X = T2 @ Ww^T + Wb  (T2 in Ot, Wt[l][j] = Ww[j][l]) ----
  #pragma unroll
  for (int s = 0; s < R; ++s) acc[s] = wb[j];
  #pragma unroll
  for (int k0 = 0; k0 < 32; k0 += 4) {
    float4 a[R];
    #pragma unroll
    for (int s = 0; s < R; ++s)
      a[s] = *(const float4*)&Ot[(ib + s * RS) * 32 + k0];
    #pragma unroll
    for (int kk = 0; kk < 4; ++kk) {
      float bv = Wt[(k0 + kk) * 32 + j];
      #pragma unroll
      for (int s = 0; s < R; ++s)
        acc[s] = fmaf(((const float*)&a[s])[kk], bv, acc[s]);
    }
  }

  // ---- LayerNorm over 1024 + gamma/beta + ReLU ----
  float s1 = 0.f, s2 = 0.f;
  #pragma unroll
  for (int s = 0; s < R; ++s) { s1 += acc[s]; s2 += acc[s] * acc[s]; }
  wave_reduce(s1, s2);
  if ((ug & 63) == 0) { red_s[wv] = s1; red_ss[wv] = s2; }
  __syncthreads();   // also guarantees all matmul3 reads of Ot are done
  float S = 0.f, SS = 0.f;
  #pragma unroll
  for (int w = 0; w < NW; ++w) { S += red_s[wgrp + w]; SS += red_ss[wgrp + w]; }
  const float mu = S * (1.0f / 1024.0f);
  const float rs = rsqrtf(SS * (1.0f / 1024.0f) - mu * mu + LN_EPS);
  #pragma unroll
  for (int s = 0; s < R; ++s) {
    int row = ib + s * RS;
    int idx = row * 32 + j;
    float y = (acc[s] - mu) * rs * gl[idx] + bl[idx];
    Ot[row * 32 + j] = fmaxf(y, 0.f);
  }
  __syncthreads();
}

// ---- K1: leaves (level 10) + level 9 + level 8; 256 blocks x 512 thr ----
__global__ __launch_bounds__(512) void k_bottom(
    const int* __restrict__ word_ids, const float* __restrict__ emb,
    const float* __restrict__ Ww, const float* __restrict__ Wb,
    const float* __restrict__ g, const float* __restrict__ b,
    float* __restrict__ h8) {
  __shared__ float pool[6 * 1024];
  __shared__ float gl[1024], bl[1024], Wt[1024], wb[32];
  __shared__ float red_s[8], red_ss[8];
  const int u = threadIdx.x;
  const int blk = blockIdx.x;
  const int wv = u >> 6;

  stage_params(u, 512, g, b, Ww, Wb, gl, bl, Wt, wb);

  // leaves: 4 per block, 2 waves each
  {
    const int l = u >> 7;          // 0..3
    const int v = u & 127;
    const int wid = word_ids[1023 + blk * 4 + l];
    const float4* src = (const float4*)(emb + (size_t)wid * 1024);
    float4 x0 = src[v], x1 = src[v + 128];
    float s1 = (x0.x + x0.y) + (x0.z + x0.w) + (x1.x + x1.y) + (x1.z + x1.w);
    float s2 = x0.x * x0.x + x0.y * x0.y + x0.z * x0.z + x0.w * x0.w +
               x1.x * x1.x + x1.y * x1.y + x1.z * x1.z + x1.w * x1.w;
    wave_reduce(s1, s2);
    if ((u & 63) == 0) { red_s[wv] = s1; red_ss[wv] = s2; }
    __syncthreads();  // red visible; also params staged
    const float S = red_s[2 * l] + red_s[2 * l + 1];
    const float SS = red_ss[2 * l] + red_ss[2 * l + 1];
    const float mu = S * (1.0f / 1024.0f);
    const float rs = rsqrtf(SS * (1.0f / 1024.0f) - mu * mu + LN_EPS);
    float* tp = pool + l * 1024;
    float4 g4 = ((const float4*)gl)[v], b4 = ((const float4*)bl)[v];
    float4 y;
    y.x = fmaxf((x0.x - mu) * rs * g4.x + b4.x, 0.f);
    y.y = fmaxf((x0.y - mu) * rs * g4.y + b4.y, 0.f);
    y.z = fmaxf((x0.z - mu) * rs * g4.z + b4.z, 0.f);
    y.w = fmaxf((x0.w - mu) * rs * g4.w + b4.w, 0.f);
    ((float4*)tp)[v] = y;
    g4 = ((const float4*)gl)[v + 128]; b4 = ((const float4*)bl)[v + 128];
    y.x = fmaxf((x1.x - mu) * rs * g4.x + b4.x, 0.f);
    y.y = fmaxf((x1.y - mu) * rs * g4.y + b4.y, 0.f);
    y.z = fmaxf((x1.z - mu) * rs * g4.z + b4.z, 0.f);
    y.w = fmaxf((x1.w - mu) * rs * g4.w + b4.w, 0.f);
    ((float4*)tp)[v + 128] = y;
    __syncthreads();
  }

  // level 9: 2 nodes in parallel, NW=4 each (outputs -> tiles 4,5)
  {
    const int m = u >> 8;          // 0..1
    const int ug = u & 255;
    const int id = 511 + blk * 2 + m;
    float* Ot = pool + (4 + m) * 1024;
    copy_tile(ug, 256, emb + (size_t)word_ids[id] * 1024, Ot);
    node_compute<4>(ug, wv, m * 4, pool + (2 * m) * 1024,
                    pool + (2 * m + 1) * 1024, Ot, Wt, wb, gl, bl, red_s, red_ss);
  }

  // level 8: 1 node, NW=8 (children tiles 4,5; output -> tile 0)
  {
    const int id = 255 + blk;
    float* Ot = pool;
    copy_tile(u, 512, emb + (size_t)word_ids[id] * 1024, Ot);
    node_compute<8>(u, wv, 0, pool + 4 * 1024, pool + 5 * 1024, Ot, Wt, wb, gl,
                    bl, red_s, red_ss);
  }

  copy_tile(u, 512, pool, h8 + (size_t)blk * 1024);
}

// ---- K2..K5: two levels per kernel. Block b: child nodes (2b,2b+1) from
// h_in[4b..4b+3], then parent node b. 512 thr, NW=4 pair + NW=8 parent. ----
__global__ __launch_bounds__(512) void k_pair(
    const int* __restrict__ word_ids, const float* __restrict__ emb,
    const float* __restrict__ Ww, const float* __restrict__ Wb,
    const float* __restrict__ g, const float* __restrict__ b,
    const float* __restrict__ Pw, const float* __restrict__ Pb,
    const int* __restrict__ label, const float* __restrict__ h_in,
    float* __restrict__ h_out, float* __restrict__ out, int sc, int sp) {
  __shared__ float pool[6 * 1024];
  __shared__ float gl[1024], bl[1024], Wt[1024], wb[32];
  __shared__ float red_s[8], red_ss[8];
  const int u = threadIdx.x;
  const int blk = blockIdx.x;
  const int wv = u >> 6;

  stage_params(u, 512, g, b, Ww, Wb, gl, bl, Wt, wb);

  // stage 4 child tiles (0..3) and 2 emb C tiles (4,5), pair-wise
  {
    const int half = u >> 8;        // 0..1
    const int uh = u & 255;
    copy_tile(uh, 256, h_in + (size_t)(4 * blk + half) * 1024,
              pool + half * 1024);
    copy_tile(uh, 256, h_in + (size_t)(4 * blk + 2 + half) * 1024,
              pool + (2 + half) * 1024);
    copy_tile(uh, 256,
              emb + (size_t)word_ids[sc + 2 * blk + half] * 1024,
              pool + (4 + half) * 1024);
  }
  __syncthreads();

  // two child nodes in parallel, NW=4: A:{L=0,R=1,Ot=4}, B:{L=2,R=3,Ot=5}
  {
    const int m = u >> 8;
    const int ug = u & 255;
    node_compute<4>(ug, wv, m * 4, pool + (2 * m) * 1024,
                    pool + (2 * m + 1) * 1024, pool + (4 + m) * 1024, Wt, wb,
                    gl, bl, red_s, red_ss);
  }

  // parent, NW=8: L=4, R=5, C/out -> tile 1 (dead, not anyone's scratch)
  copy_tile(u, 512, emb + (size_t)word_ids[sp + blk] * 1024, pool + 1024);
  node_compute<8>(u, wv, 0, pool + 4 * 1024, pool + 5 * 1024, pool + 1024, Wt,
                  wb, gl, bl, red_s, red_ss);

  if (h_out) {
    copy_tile(u, 512, pool + 1024, h_out + (size_t)blk * 1024);
  } else {
    // fused head: root in tile 1; wave 0 only, all in-register
    if (wv == 0) {
      const int lane = u & 63;
      float logits[10];
      #pragma unroll
      for (int c = 0; c < 10; ++c) {
        float p = 0.f;
        #pragma unroll
        for (int q = 0; q < 16; ++q) {
          int e = q * 64 + lane;
          p += pool[1024 + e] * Pw[c * 1024 + e];
        }
        #pragma unroll
        for (int off = 32; off; off >>= 1) p += __shfl_xor(p, off);
        logits[c] = p + Pb[c];
      }
      if (u == 0) {
        float mmax = logits[0];
        int am = 0;
        #pragma unroll
        for (int c = 1; c < 10; ++c)
          if (logits[c] > mmax) { mmax = logits[c]; am = c; }
        float sum = 0.f;
        #pragma unroll
        for (int c = 0; c < 10; ++c) sum += expf(logits[c] - mmax);
        float loss = -(logits[label[0]] - mmax - logf(sum));
        out[0] = (float)am;
        out[1] = loss;
      }
    }
  }
}

extern "C" void kernel_launch(void* const* d_in, const int* in_sizes, int n_in,
                              void* d_out, int out_size, void* d_ws, size_t ws_size,
                              hipStream_t stream) {
  const int* word_ids = (const int*)d_in[0];
  const int* label = (const int*)d_in[1];
  const float* emb = (const float*)d_in[2];
  const float* Ww = (const float*)d_in[3];
  const float* Wb = (const float*)d_in[4];
  const float* g = (const float*)d_in[5];
  const float* b = (const float*)d_in[6];
  const float* Pw = (const float*)d_in[7];
  const float* Pb = (const float*)d_in[8];
  float* out = (float*)d_out;

  float* h8 = (float*)d_ws;          // 256 tiles (level 8)
  float* h6 = h8 + 256 * 1024;       // 64 tiles  (level 6)
  float* h4 = h6 + 64 * 1024;        // 16 tiles  (level 4)
  float* h2 = h4 + 16 * 1024;        // 4 tiles   (level 2)

  k_bottom<<<256, 512, 0, stream>>>(word_ids, emb, Ww, Wb, g, b, h8);
  // levels (7,6): child word base 127, parent base 63
  k_pair<<<64, 512, 0, stream>>>(word_ids, emb, Ww, Wb, g, b, Pw, Pb, label,
                                 h8, h6, out, 127, 63);
  // levels (5,4): bases 31, 15
  k_pair<<<16, 512, 0, stream>>>(word_ids, emb, Ww, Wb, g, b, Pw, Pb, label,
                                 h6, h4, out, 31, 15);
  // levels (3,2): bases 7, 3
  k_pair<<<4, 512, 0, stream>>>(word_ids, emb, Ww, Wb, g, b, Pw, Pb, label,
                                 h4, h2, out, 7, 3);
  // levels (1,0) + head: bases 1, 0
  k_pair<<<1, 512, 0, stream>>>(word_ids, emb, Ww, Wb, g, b, Pw, Pb, label,
                                 h2, nullptr, out, 1, 0);
}

// Round 4
// 73.204 us; speedup vs baseline: 1.3730x; 1.1280x over previous
//
#include <hip/hip_runtime.h>

#define LN_EPS 1e-5f
#define TS 36            // LDS tile row stride in floats (144B: 16B-aligned)
#define TILE (32 * TS)   // one 32x32 tile with padding

__device__ __forceinline__ void wave_reduce2(float& s1, float& s2) {
  #pragma unroll
  for (int off = 32; off; off >>= 1) {
    s1 += __shfl_xor(s1, off);
    s2 += __shfl_xor(s2, off);
  }
}

// stage a 32x32 row-major global tile into LDS [32][TS], optionally transposed
__device__ __forceinline__ void stage_tile(float* dst, const float* __restrict__ src,
                                           int i0, int j0, bool transp) {
  float x[4][4];
  #pragma unroll
  for (int rr = 0; rr < 4; ++rr)
    *(float4*)x[rr] = *(const float4*)&src[(i0 + rr) * 32 + j0];
  if (transp) {
    #pragma unroll
    for (int cc = 0; cc < 4; ++cc) {
      float4 w = make_float4(x[0][cc], x[1][cc], x[2][cc], x[3][cc]);
      *(float4*)&dst[(j0 + cc) * TS + i0] = w;
    }
  } else {
    #pragma unroll
    for (int rr = 0; rr < 4; ++rr)
      *(float4*)&dst[(i0 + rr) * TS + j0] = *(float4*)x[rr];
  }
}

// acc(4x4) = A @ B where At is A stored transposed (At[k][i]), Bn normal (B[k][j])
__device__ __forceinline__ void mm4x4(const float* At, const float* Bn,
                                      int i0, int j0, float acc[4][4]) {
  #pragma unroll
  for (int ii = 0; ii < 4; ++ii)
    #pragma unroll
    for (int jj = 0; jj < 4; ++jj) acc[ii][jj] = 0.f;
  #pragma unroll 8
  for (int k = 0; k < 32; ++k) {
    float4 av = *(const float4*)&At[k * TS + i0];
    float4 bv = *(const float4*)&Bn[k * TS + j0];
    const float* ap = (const float*)&av;
    const float* bp = (const float*)&bv;
    #pragma unroll
    for (int ii = 0; ii < 4; ++ii)
      #pragma unroll
      for (int jj = 0; jj < 4; ++jj)
        acc[ii][jj] = fmaf(ap[ii], bp[jj], acc[ii][jj]);
  }
}

__device__ __forceinline__ void wr_transp(float* dst, const float acc[4][4],
                                          int i0, int j0) {
  #pragma unroll
  for (int cc = 0; cc < 4; ++cc) {
    float4 w = make_float4(acc[0][cc], acc[1][cc], acc[2][cc], acc[3][cc]);
    *(float4*)&dst[(j0 + cc) * TS + i0] = w;
  }
}

__device__ __forceinline__ void wr_norm(float* dst, const float acc[4][4],
                                        int i0, int j0) {
  #pragma unroll
  for (int rr = 0; rr < 4; ++rr) {
    float4 w = make_float4(acc[rr][0], acc[rr][1], acc[rr][2], acc[rr][3]);
    *(float4*)&dst[(i0 + rr) * TS + j0] = w;
  }
}

// One full tree node on ONE wave. Lt = left child transposed, Rn = right child
// normal, Cn = emb tile normal. h = relu(LN((L@R@C)@Ww^T + Wb)) -> Cn slot.
// T1^T scratch overwrites Lt, T2^T overwrites Rn (in-wave ds ordering + data
// deps make this safe; compiler inserts lgkmcnt waits).
__device__ __forceinline__ void node_wave(float* Lt, float* Rn, float* Cn,
                                          const float* Wwt, int i0, int j0,
                                          const float4 wbv,
                                          const float g[4][4], const float be[4][4],
                                          bool transpOut) {
  float acc[4][4];
  mm4x4(Lt, Rn, i0, j0, acc);
  wr_transp(Lt, acc, i0, j0);           // T1^T
  mm4x4(Lt, Cn, i0, j0, acc);
  wr_transp(Rn, acc, i0, j0);           // T2^T
  mm4x4(Rn, Wwt, i0, j0, acc);
  const float* wbp = (const float*)&wbv;
  float s1 = 0.f, s2 = 0.f;
  #pragma unroll
  for (int ii = 0; ii < 4; ++ii)
    #pragma unroll
    for (int jj = 0; jj < 4; ++jj) {
      acc[ii][jj] += wbp[jj];
      s1 += acc[ii][jj];
      s2 += acc[ii][jj] * acc[ii][jj];
    }
  wave_reduce2(s1, s2);                 // LN stats, zero barriers
  const float mu = s1 * (1.0f / 1024.0f);
  const float rs = rsqrtf(s2 * (1.0f / 1024.0f) - mu * mu + LN_EPS);
  #pragma unroll
  for (int ii = 0; ii < 4; ++ii)
    #pragma unroll
    for (int jj = 0; jj < 4; ++jj)
      acc[ii][jj] = fmaxf((acc[ii][jj] - mu) * rs * g[ii][jj] + be[ii][jj], 0.f);
  if (transpOut) wr_transp(Cn, acc, i0, j0);
  else wr_norm(Cn, acc, i0, j0);
}

// ---- K1: leaves + level 9 + level 8; 256 blocks x 256 thr (4 waves) ----
__global__ __launch_bounds__(256) void k_bottom(
    const int* __restrict__ word_ids, const float* __restrict__ emb,
    const float* __restrict__ Ww, const float* __restrict__ Wb,
    const float* __restrict__ gamma, const float* __restrict__ beta,
    float* __restrict__ h8) {
  __shared__ float pool[8 * TILE];
  const int u = threadIdx.x, blk = blockIdx.x;
  const int wv = u >> 6, ln = u & 63;
  const int i0 = (ln >> 3) * 4, j0 = (ln & 7) * 4;

  float g[4][4], be[4][4];
  #pragma unroll
  for (int rr = 0; rr < 4; ++rr) {
    *(float4*)g[rr] = *(const float4*)&gamma[(i0 + rr) * 32 + j0];
    *(float4*)be[rr] = *(const float4*)&beta[(i0 + rr) * 32 + j0];
  }
  const float4 wbv = *(const float4*)&Wb[j0];

  // role staging: C tiles for L9-A (t2), L9-B (t5), L8 (t6); Ww^T (t7)
  if (wv == 0)
    stage_tile(pool + 2 * TILE, emb + (size_t)word_ids[511 + 2 * blk] * 1024, i0, j0, false);
  else if (wv == 1)
    stage_tile(pool + 5 * TILE, emb + (size_t)word_ids[511 + 2 * blk + 1] * 1024, i0, j0, false);
  else if (wv == 2)
    stage_tile(pool + 6 * TILE, emb + (size_t)word_ids[255 + blk] * 1024, i0, j0, false);
  else
    stage_tile(pool + 7 * TILE, Ww, i0, j0, true);

  // leaf: one per wave; even leaf -> left child (transposed)
  {
    const int wid = word_ids[1023 + 4 * blk + wv];
    const float* src = emb + (size_t)wid * 1024;
    float x[4][4];
    float s1 = 0.f, s2 = 0.f;
    #pragma unroll
    for (int rr = 0; rr < 4; ++rr) {
      *(float4*)x[rr] = *(const float4*)&src[(i0 + rr) * 32 + j0];
      #pragma unroll
      for (int cc = 0; cc < 4; ++cc) { s1 += x[rr][cc]; s2 += x[rr][cc] * x[rr][cc]; }
    }
    wave_reduce2(s1, s2);
    const float mu = s1 * (1.0f / 1024.0f);
    const float rs = rsqrtf(s2 * (1.0f / 1024.0f) - mu * mu + LN_EPS);
    #pragma unroll
    for (int rr = 0; rr < 4; ++rr)
      #pragma unroll
      for (int cc = 0; cc < 4; ++cc)
        x[rr][cc] = fmaxf((x[rr][cc] - mu) * rs * g[rr][cc] + be[rr][cc], 0.f);
    const int slot = (wv < 2) ? wv : wv + 1;   // slots 0,1,3,4
    if ((wv & 1) == 0) wr_transp(pool + slot * TILE, x, i0, j0);
    else wr_norm(pool + slot * TILE, x, i0, j0);
  }
  __syncthreads();

  // L9: wave 0 -> node A (out transposed to t2), wave 1 -> node B (normal to t5)
  if (wv < 2)
    node_wave(pool + (3 * wv) * TILE, pool + (3 * wv + 1) * TILE,
              pool + (3 * wv + 2) * TILE, pool + 7 * TILE, i0, j0, wbv, g, be,
              wv == 0);
  __syncthreads();

  // L8: wave 0: Lt=t2, Rn=t5, Cn=t6 -> h normal in t6
  if (wv == 0)
    node_wave(pool + 2 * TILE, pool + 5 * TILE, pool + 6 * TILE, pool + 7 * TILE,
              i0, j0, wbv, g, be, false);
  __syncthreads();

  {
    const int r = u >> 3, c = (u & 7) * 4;
    *(float4*)&h8[(size_t)blk * 1024 + r * 32 + c] =
        *(float4*)&pool[6 * TILE + r * TS + c];
  }
}

// ---- K2..K5: two levels per kernel; 1 wave per node; optional fused head ----
__global__ __launch_bounds__(256) void k_pair(
    const int* __restrict__ word_ids, const float* __restrict__ emb,
    const float* __restrict__ Ww, const float* __restrict__ Wb,
    const float* __restrict__ gamma, const float* __restrict__ beta,
    const float* __restrict__ Pw, const float* __restrict__ Pb,
    const int* __restrict__ label, const float* __restrict__ h_in,
    float* __restrict__ h_out, float* __restrict__ out, int sc, int sp) {
  __shared__ float pool[8 * TILE];
  const int u = threadIdx.x, blk = blockIdx.x;
  const int wv = u >> 6, ln = u & 63;
  const int i0 = (ln >> 3) * 4, j0 = (ln & 7) * 4;

  float g[4][4], be[4][4];
  #pragma unroll
  for (int rr = 0; rr < 4; ++rr) {
    *(float4*)g[rr] = *(const float4*)&gamma[(i0 + rr) * 32 + j0];
    *(float4*)be[rr] = *(const float4*)&beta[(i0 + rr) * 32 + j0];
  }
  const float4 wbv = *(const float4*)&Wb[j0];

  // child tiles from global: slots 0,1,3,4; even position -> transposed (left)
  {
    const int slot = (wv < 2) ? wv : wv + 1;
    stage_tile(pool + slot * TILE, h_in + (size_t)(4 * blk + wv) * 1024, i0, j0,
               (wv & 1) == 0);
  }
  // role staging
  if (wv == 0)
    stage_tile(pool + 2 * TILE, emb + (size_t)word_ids[sc + 2 * blk] * 1024, i0, j0, false);
  else if (wv == 1)
    stage_tile(pool + 5 * TILE, emb + (size_t)word_ids[sc + 2 * blk + 1] * 1024, i0, j0, false);
  else if (wv == 2)
    stage_tile(pool + 6 * TILE, emb + (size_t)word_ids[sp + blk] * 1024, i0, j0, false);
  else
    stage_tile(pool + 7 * TILE, Ww, i0, j0, true);
  __syncthreads();

  // child level: 2 nodes on waves 0,1
  if (wv < 2)
    node_wave(pool + (3 * wv) * TILE, pool + (3 * wv + 1) * TILE,
              pool + (3 * wv + 2) * TILE, pool + 7 * TILE, i0, j0, wbv, g, be,
              wv == 0);
  __syncthreads();

  // parent: wave 0
  if (wv == 0)
    node_wave(pool + 2 * TILE, pool + 5 * TILE, pool + 6 * TILE, pool + 7 * TILE,
              i0, j0, wbv, g, be, false);
  __syncthreads();

  if (h_out) {
    const int r = u >> 3, c = (u & 7) * 4;
    *(float4*)&h_out[(size_t)blk * 1024 + r * 32 + c] =
        *(float4*)&pool[6 * TILE + r * TS + c];
  } else if (wv == 0) {
    // head: root in t6 (normal layout, stride TS)
    float logits[10];
    #pragma unroll
    for (int c = 0; c < 10; ++c) {
      float p = 0.f;
      #pragma unroll
      for (int q = 0; q < 16; ++q) {
        const int e = q * 64 + ln;
        const int r = e >> 5, cc = e & 31;
        p += pool[6 * TILE + r * TS + cc] * Pw[c * 1024 + e];
      }
      #pragma unroll
      for (int off = 32; off; off >>= 1) p += __shfl_xor(p, off);
      logits[c] = p + Pb[c];
    }
    if (u == 0) {
      float mmax = logits[0];
      int am = 0;
      #pragma unroll
      for (int c = 1; c < 10; ++c)
        if (logits[c] > mmax) { mmax = logits[c]; am = c; }
      float sum = 0.f;
      #pragma unroll
      for (int c = 0; c < 10; ++c) sum += expf(logits[c] - mmax);
      float loss = -(logits[label[0]] - mmax - logf(sum));
      out[0] = (float)am;
      out[1] = loss;
    }
  }
}

extern "C" void kernel_launch(void* const* d_in, const int* in_sizes, int n_in,
                              void* d_out, int out_size, void* d_ws, size_t ws_size,
                              hipStream_t stream) {
  const int* word_ids = (const int*)d_in[0];
  const int* label = (const int*)d_in[1];
  const float* emb = (const float*)d_in[2];
  const float* Ww = (const float*)d_in[3];
  const float* Wb = (const float*)d_in[4];
  const float* g = (const float*)d_in[5];
  const float* b = (const float*)d_in[6];
  const float* Pw = (const float*)d_in[7];
  const float* Pb = (const float*)d_in[8];
  float* out = (float*)d_out;

  float* h8 = (float*)d_ws;          // 256 tiles (level 8)
  float* h6 = h8 + 256 * 1024;       // 64 tiles  (level 6)
  float* h4 = h6 + 64 * 1024;        // 16 tiles  (level 4)
  float* h2 = h4 + 16 * 1024;        // 4 tiles   (level 2)

  k_bottom<<<256, 256, 0, stream>>>(word_ids, emb, Ww, Wb, g, b, h8);
  // levels (7,6): child base 127, parent base 63
  k_pair<<<64, 256, 0, stream>>>(word_ids, emb, Ww, Wb, g, b, Pw, Pb, label,
                                 h8, h6, out, 127, 63);
  // levels (5,4): bases 31, 15
  k_pair<<<16, 256, 0, stream>>>(word_ids, emb, Ww, Wb, g, b, Pw, Pb, label,
                                 h6, h4, out, 31, 15);
  // levels (3,2): bases 7, 3
  k_pair<<<4, 256, 0, stream>>>(word_ids, emb, Ww, Wb, g, b, Pw, Pb, label,
                                 h4, h2, out, 7, 3);
  // levels (1,0) + head: bases 1, 0
  k_pair<<<1, 256, 0, stream>>>(word_ids, emb, Ww, Wb, g, b, Pw, Pb, label,
                                 h2, nullptr, out, 1, 0);
}